// Round 4
// baseline (1254.357 us; speedup 1.0000x reference)
//
#include <hip/hip_runtime.h>

#define N_NODES 100000
#define N_EDGES 1600000
#define DIM 256

typedef unsigned short bf16u;
typedef __attribute__((ext_vector_type(8))) short bf16x8s;
typedef __attribute__((ext_vector_type(4))) float f32x4;

__device__ __forceinline__ float bf2f(unsigned int u16) {
    union { unsigned int i; float f; } x; x.i = u16 << 16; return x.f;
}
__device__ __forceinline__ bf16u f2bf(float f) {
    union { float f; unsigned int i; } x; x.f = f;
    unsigned int i = x.i;
    return (bf16u)((i + 0x7fffu + ((i >> 16) & 1u)) >> 16);
}
// dual-dtype load: isf32 ? float32 : bf16
__device__ __forceinline__ float loadv(const void* p, size_t i, int isf32) {
    return isf32 ? ((const float*)p)[i] : bf2f(((const bf16u*)p)[i]);
}

// ---------------- zero helpers (no hipMemsetAsync) ----------------
__global__ void zero_ints(int* p, int n) {
    int i = blockIdx.x * 256 + threadIdx.x;
    if (i < n) p[i] = 0;
}
__global__ void zero_floats(float* p, int n) {
    int i = blockIdx.x * 256 + threadIdx.x;
    if (i < n) p[i] = 0.f;
}

// ---------------- runtime format probes ----------------
// flags[0]=x is float32; flags[1]=edge stride (1=int32,2=int64); flags[2]=dst word base
__global__ void detect_flags(const unsigned* xw, const int* ei, int* flags) {
    __shared__ int cnt, nz;
    if (threadIdx.x == 0) { cnt = 0; nz = 0; }
    __syncthreads();
    // low 16 bits of each 32-bit word: bf16 stream -> a real bf16 value; f32 stream -> mantissa garbage
    unsigned u = xw[threadIdx.x];
    float v = bf2f(u & 0xffffu);
    float av = fabsf(v);
    if (av > 1e-5f && av < 50.f) atomicAdd(&cnt, 1);
    // int64 edge_index: odd words are high halves of ids < 2^31 -> all zero
    if (ei[2 * threadIdx.x + 1] != 0) atomicAdd(&nz, 1);
    __syncthreads();
    if (threadIdx.x == 0) {
        flags[0] = (cnt >= 128) ? 0 /*bf16*/ : 1 /*f32*/;
        if (cnt >= 128) flags[0] = 0; else flags[0] = 1;
        if (nz == 0) { flags[1] = 2; flags[2] = 2 * N_EDGES; }
        else         { flags[1] = 1; flags[2] = N_EDGES; }
    }
}

// ---------------- weight transpose: Wt[n][k] = bf16(W[k][n]), 4 weights ----------------
__global__ void transpose_w(const void* W0, const void* W1, const void* W2, const void* W3,
                            bf16u* Wt, const int* flags) {
    __shared__ bf16u tile[64][65];
    int isf32 = flags[0];
    const void* W = (blockIdx.y == 0) ? W0 : (blockIdx.y == 1) ? W1 : (blockIdx.y == 2) ? W2 : W3;
    bf16u* out = Wt + (size_t)blockIdx.y * DIM * DIM;
    int t = threadIdx.x;
    int tx = t & 63, ty = t >> 6;
    int k0 = (blockIdx.x >> 2) * 64, n0 = (blockIdx.x & 3) * 64;
#pragma unroll
    for (int i = 0; i < 16; ++i) {
        int r = ty + i * 4;
        tile[tx][r] = f2bf(loadv(W, (size_t)(k0 + r) * DIM + (n0 + tx), isf32));
    }
    __syncthreads();
#pragma unroll
    for (int i = 0; i < 16; ++i) {
        int r = ty + i * 4;
        out[(size_t)(n0 + r) * DIM + (k0 + tx)] = tile[r][tx];
    }
}

// ---------------- column stats: sums[0..255]=sum, sums[256..511]=sumsq ----------------
// dual==1: X dtype decided by flags[0]; dual==0: X is bf16 (internal buffer)
__global__ void col_stats(const void* X, int nrows, float* sums, const int* flags, int dual) {
    __shared__ float ls[512];
    int isf32 = dual ? flags[0] : 0;
    int t = threadIdx.x;
    ls[t] = 0.f; ls[t + 256] = 0.f;
    __syncthreads();
    int rpb = (nrows + gridDim.x - 1) / gridDim.x;
    int r0 = blockIdx.x * rpb;
    int r1 = r0 + rpb; if (r1 > nrows) r1 = nrows;
    int cg = (t & 31) * 8;
    float s[8], q[8];
#pragma unroll
    for (int j = 0; j < 8; ++j) { s[j] = 0.f; q[j] = 0.f; }
    for (int r = r0 + (t >> 5); r < r1; r += 8) {
        size_t base = (size_t)r * DIM + cg;
#pragma unroll
        for (int j = 0; j < 8; ++j) {
            float f = loadv(X, base + j, isf32);
            s[j] += f; q[j] += f * f;
        }
    }
#pragma unroll
    for (int j = 0; j < 8; ++j) {
        atomicAdd(&ls[cg + j], s[j]);
        atomicAdd(&ls[256 + cg + j], q[j]);
    }
    __syncthreads();
    atomicAdd(&sums[t], ls[t]);
    atomicAdd(&sums[256 + t], ls[256 + t]);
}

__global__ void bn_finalize(const float* sums, const void* gamma, const void* beta,
                            float* sc, float* sh, float inv_n, const int* flags) {
    int isf32 = flags[0];
    int t = threadIdx.x;
    float mu = sums[t] * inv_n;
    float var = sums[256 + t] * inv_n - mu * mu;
    float rs = rsqrtf(var + 1e-5f);
    float g = loadv(gamma, t, isf32), b = loadv(beta, t, isf32);
    sc[t] = rs * g;
    sh[t] = b - mu * rs * g;
}

// y = relu?(x*sc+sh); writes bf16. dual: X dtype from flags.
__global__ void bn_apply(const void* X, const float* sc, const float* sh, bf16u* Y,
                         const int* flags, int dual, int relu) {
    int isf32 = dual ? flags[0] : 0;
    size_t i = (size_t)blockIdx.x * 256 + threadIdx.x;   // one 8-elem chunk per thread
    int c = ((int)i * 8) & 255;
    size_t base = i * 8;
    bf16u tmp[8];
#pragma unroll
    for (int j = 0; j < 8; ++j) {
        float y = loadv(X, base + j, isf32) * sc[c + j] + sh[c + j];
        if (relu) y = fmaxf(y, 0.f);
        tmp[j] = f2bf(y);
    }
    bf16u* o = Y + base;
#pragma unroll
    for (int j = 0; j < 8; ++j) o[j] = tmp[j];
}

// ---------------- CSR build ----------------
__global__ void edge_hist(const int* ei, const int* flags, int* deg) {
    int e = blockIdx.x * 256 + threadIdx.x;
    if (e < N_EDGES) {
        int d = ei[(size_t)flags[2] + (size_t)e * flags[1]];
        atomicAdd(&deg[d], 1);
    }
}

__global__ void scan1(const int* deg, int* rp, int* bsum) {
    __shared__ int s[256];
    int t = threadIdx.x;
    int i = blockIdx.x * 256 + t;
    s[t] = (i < N_NODES) ? deg[i] : 0;
    __syncthreads();
    for (int off = 1; off < 256; off <<= 1) {
        int nv = (t >= off) ? s[t - off] : 0;
        __syncthreads();
        s[t] += nv;
        __syncthreads();
    }
    if (i < N_NODES) rp[i + 1] = s[t];
    if (t == 255) bsum[blockIdx.x] = s[255];
}

__global__ void scan2(int* bsum, int nblocks) {
    __shared__ int s[512];
    int t = threadIdx.x;
    s[t] = (t < nblocks) ? bsum[t] : 0;
    __syncthreads();
    for (int off = 1; off < 512; off <<= 1) {
        int nv = (t >= off) ? s[t - off] : 0;
        __syncthreads();
        s[t] += nv;
        __syncthreads();
    }
    if (t < nblocks) bsum[t] = s[t];
}

__global__ void scan3(int* rp, const int* bsum) {
    int i = blockIdx.x * 256 + threadIdx.x;
    if (i == 0) rp[0] = 0;
    if (i < N_NODES) {
        int b = i >> 8;
        if (b > 0) rp[i + 1] += bsum[b - 1];
    }
}

__global__ void csr_fill(const int* ei, const int* flags, const int* rp, int* fill, int* col) {
    int e = blockIdx.x * 256 + threadIdx.x;
    if (e < N_EDGES) {
        int d = ei[(size_t)flags[2] + (size_t)e * flags[1]];
        int s = ei[(size_t)e * flags[1]];
        int p = rp[d] + atomicAdd(&fill[d], 1);
        col[p] = s;
    }
}

// ---------------- aggregation: out[i] = h[i] + sum_{j in N(i)} h[j] (bf16 in/out) ----------------
__global__ void aggregate(const bf16u* h, const int* rp, const int* col, bf16u* out) {
    int node = blockIdx.x * 4 + (threadIdx.x >> 6);
    int lane = threadIdx.x & 63;
    int coff = lane * 4;
    const bf16u* base = h + coff;
    unsigned int u0 = *(const unsigned int*)(h + (size_t)node * DIM + coff);
    unsigned int u1 = *(const unsigned int*)(h + (size_t)node * DIM + coff + 2);
    float a0 = bf2f(u0 & 0xffffu), a1 = bf2f(u0 >> 16);
    float a2 = bf2f(u1 & 0xffffu), a3 = bf2f(u1 >> 16);
    int e0 = rp[node], e1 = rp[node + 1];
    for (int e = e0; e < e1; ++e) {
        int s = col[e];
        unsigned int w0 = *(const unsigned int*)(base + (size_t)s * DIM);
        unsigned int w1 = *(const unsigned int*)(base + (size_t)s * DIM + 2);
        a0 += bf2f(w0 & 0xffffu); a1 += bf2f(w0 >> 16);
        a2 += bf2f(w1 & 0xffffu); a3 += bf2f(w1 >> 16);
    }
    bf16u* o = out + (size_t)node * DIM + coff;
    o[0] = f2bf(a0); o[1] = f2bf(a1); o[2] = f2bf(a2); o[3] = f2bf(a3);
}

// ---------------- MFMA GEMM: C[M x 256] = A(bf16) @ W + bias, optional relu ----------------
// Wt is bf16 [n][k]. bias dtype = flags[0]. If f32out!=0 and flags[0], store f32, else bf16.
__global__ __launch_bounds__(256) void gemm_bias(const bf16u* __restrict__ A,
                                                 const bf16u* __restrict__ Wt,
                                                 const void* __restrict__ bias,
                                                 void* __restrict__ Cout, int mrows,
                                                 const int* flags, int relu, int f32out) {
    __shared__ bf16u As[128 * 32];
    __shared__ bf16u Bs[128 * 32];
    int isf32 = flags[0];
    int t = threadIdx.x;
    int w = t >> 6, lane = t & 63;
    int lr = lane & 15, lq = lane >> 4;
    int wm = w >> 1, wn = w & 1;
    int rowBase = blockIdx.x * 128, colBase = blockIdx.y * 128;
    f32x4 acc[4][4] = {};
    int row = t >> 2, kp = t & 3;          // 64 rows x 4 k-chunks per pass
    for (int k0 = 0; k0 < 256; k0 += 32) {
        __syncthreads();
#pragma unroll
        for (int i = 0; i < 2; ++i) {
            int r = row + (i << 6);
            int gr = rowBase + r; gr = (gr < mrows) ? gr : (mrows - 1);
            bf16x8s av = *(const bf16x8s*)(A + (size_t)gr * 256 + k0 + kp * 8);
            bf16x8s bv = *(const bf16x8s*)(Wt + (size_t)(colBase + r) * 256 + k0 + kp * 8);
            *(bf16x8s*)&As[r * 32 + kp * 8] = av;
            *(bf16x8s*)&Bs[r * 32 + kp * 8] = bv;
        }
        __syncthreads();
        bf16x8s af[4], bfv[4];
#pragma unroll
        for (int mt = 0; mt < 4; ++mt)
            af[mt] = *(const bf16x8s*)&As[(wm * 64 + mt * 16 + lr) * 32 + lq * 8];
#pragma unroll
        for (int nt = 0; nt < 4; ++nt)
            bfv[nt] = *(const bf16x8s*)&Bs[(wn * 64 + nt * 16 + lr) * 32 + lq * 8];
#pragma unroll
        for (int mt = 0; mt < 4; ++mt)
#pragma unroll
            for (int nt = 0; nt < 4; ++nt)
                acc[mt][nt] = __builtin_amdgcn_mfma_f32_16x16x32_bf16(af[mt], bfv[nt], acc[mt][nt], 0, 0, 0);
    }
    int storef32 = f32out && isf32;
#pragma unroll
    for (int nt = 0; nt < 4; ++nt) {
        int c = colBase + wn * 64 + nt * 16 + lr;
        float bv = loadv(bias, c, isf32);
#pragma unroll
        for (int mt = 0; mt < 4; ++mt) {
            int r0 = rowBase + wm * 64 + mt * 16 + lq * 4;
#pragma unroll
            for (int j = 0; j < 4; ++j) {
                int r = r0 + j;
                if (r < mrows) {
                    float y = acc[mt][nt][j] + bv;
                    if (relu) y = fmaxf(y, 0.f);
                    if (storef32) ((float*)Cout)[(size_t)r * 256 + c] = y;
                    else          ((bf16u*)Cout)[(size_t)r * 256 + c] = f2bf(y);
                }
            }
        }
    }
}

extern "C" void kernel_launch(void* const* d_in, const int* in_sizes, int n_in,
                              void* d_out, int out_size, void* d_ws, size_t ws_size,
                              hipStream_t stream) {
    const void* x   = d_in[0];
    const int*  ei  = (const int*)d_in[1];
    const void* g0  = d_in[2];
    const void* b0  = d_in[3];
    const void* W1a = d_in[4];
    const void* b1a = d_in[5];
    const void* g1  = d_in[6];
    const void* bt1 = d_in[7];
    const void* W1b = d_in[8];
    const void* b1b = d_in[9];
    const void* W2a = d_in[10];
    const void* b2a = d_in[11];
    const void* g2  = d_in[12];
    const void* bt2 = d_in[13];
    const void* W2b = d_in[14];
    const void* b2b = d_in[15];

    char* ws = (char*)d_ws;
    size_t off = 0;
    auto alloc = [&](size_t bytes) {
        char* p = ws + off;
        off += (bytes + 255) & ~(size_t)255;
        return p;
    };
    const size_t FB = (size_t)N_NODES * DIM * 2;   // 51.2 MB bf16 feature buffer
    bf16u* bufA  = (bf16u*)alloc(FB);
    bf16u* bufB  = (bf16u*)alloc(FB);
    bf16u* Wt    = (bf16u*)alloc((size_t)4 * DIM * DIM * 2);
    int*   colA  = (int*)alloc((size_t)N_EDGES * 4);
    int*   rp    = (int*)alloc((size_t)(N_NODES + 1) * 4);
    int*   deg   = (int*)alloc((size_t)N_NODES * 4);
    int*   fill  = (int*)alloc((size_t)N_NODES * 4);
    int*   bsum  = (int*)alloc(512 * 4);
    float* sums  = (float*)alloc(512 * 4);
    float* sc    = (float*)alloc(256 * 4);
    float* sh    = (float*)alloc(256 * 4);
    int*   flags = (int*)alloc(4 * 4);

    bf16u* Wt1a = Wt;
    bf16u* Wt1b = Wt + 65536;
    bf16u* Wt2a = Wt + 2 * 65536;
    bf16u* Wt2b = Wt + 3 * 65536;

    const float inv_n = 1.0f / (float)N_NODES;

    // probes first — everything downstream branches on flags (device-side, uniform)
    detect_flags<<<1, 256, 0, stream>>>((const unsigned*)x, ei, flags);

    // weights -> bf16 Wt[n][k]
    transpose_w<<<dim3(16, 4), 256, 0, stream>>>(W1a, W1b, W2a, W2b, Wt, flags);

    // CSR build
    zero_ints<<<391, 256, 0, stream>>>(deg, N_NODES);
    zero_ints<<<391, 256, 0, stream>>>(fill, N_NODES);
    edge_hist<<<6250, 256, 0, stream>>>(ei, flags, deg);
    scan1<<<391, 256, 0, stream>>>(deg, rp, bsum);
    scan2<<<1, 512, 0, stream>>>(bsum, 391);
    scan3<<<392, 256, 0, stream>>>(rp, bsum);
    csr_fill<<<6250, 256, 0, stream>>>(ei, flags, rp, fill, colA);

    // BN0: x (dual dtype) -> bufB (bf16)
    zero_floats<<<2, 256, 0, stream>>>(sums, 512);
    col_stats<<<500, 256, 0, stream>>>(x, N_NODES, sums, flags, 1);
    bn_finalize<<<1, 256, 0, stream>>>(sums, g0, b0, sc, sh, inv_n, flags);
    bn_apply<<<12500, 256, 0, stream>>>(x, sc, sh, bufB, flags, 1, 0);

    // layer 1
    aggregate<<<25000, 256, 0, stream>>>(bufB, rp, colA, bufA);
    gemm_bias<<<dim3(782, 2), 256, 0, stream>>>(bufA, Wt1a, b1a, bufB, N_NODES, flags, 0, 0);
    zero_floats<<<2, 256, 0, stream>>>(sums, 512);
    col_stats<<<500, 256, 0, stream>>>(bufB, N_NODES, sums, flags, 0);
    bn_finalize<<<1, 256, 0, stream>>>(sums, g1, bt1, sc, sh, inv_n, flags);
    bn_apply<<<12500, 256, 0, stream>>>(bufB, sc, sh, bufB, flags, 0, 1);
    gemm_bias<<<dim3(782, 2), 256, 0, stream>>>(bufB, Wt1b, b1b, bufA, N_NODES, flags, 1, 0);

    // layer 2
    aggregate<<<25000, 256, 0, stream>>>(bufA, rp, colA, bufB);
    gemm_bias<<<dim3(782, 2), 256, 0, stream>>>(bufB, Wt2a, b2a, bufA, N_NODES, flags, 0, 0);
    zero_floats<<<2, 256, 0, stream>>>(sums, 512);
    col_stats<<<500, 256, 0, stream>>>(bufA, N_NODES, sums, flags, 0);
    bn_finalize<<<1, 256, 0, stream>>>(sums, g2, bt2, sc, sh, inv_n, flags);
    bn_apply<<<12500, 256, 0, stream>>>(bufA, sc, sh, bufA, flags, 0, 1);
    // final: store width follows input dtype (f32 if inputs were f32, else bf16)
    gemm_bias<<<dim3(782, 2), 256, 0, stream>>>(bufA, Wt2b, b2b, d_out, N_NODES, flags, 1, 1);
}

// Round 5
// 967.481 us; speedup vs baseline: 1.2965x; 1.2965x over previous
//
#include <hip/hip_runtime.h>

#define N_NODES 100000
#define N_EDGES 1600000
#define DIM 256

typedef unsigned short bf16u;
typedef __attribute__((ext_vector_type(8))) short bf16x8s;
typedef __attribute__((ext_vector_type(4))) float f32x4;

__device__ __forceinline__ float bf2f(unsigned int u16) {
    union { unsigned int i; float f; } x; x.i = u16 << 16; return x.f;
}
__device__ __forceinline__ bf16u f2bf(float f) {
    union { float f; unsigned int i; } x; x.f = f;
    unsigned int i = x.i;
    return (bf16u)((i + 0x7fffu + ((i >> 16) & 1u)) >> 16);
}
__device__ __forceinline__ float loadv(const void* p, size_t i, int isf32) {
    return isf32 ? ((const float*)p)[i] : bf2f(((const bf16u*)p)[i]);
}
__device__ __forceinline__ void async_copy16(const void* g, void* l) {
    __builtin_amdgcn_global_load_lds((const __attribute__((address_space(1))) void*)g,
                                     (__attribute__((address_space(3))) void*)l, 16, 0, 0);
}

// ---------------- zero helpers ----------------
__global__ void zero_ints(int* p, int n) {
    int i = blockIdx.x * 256 + threadIdx.x;
    if (i < n) p[i] = 0;
}
__global__ void zero_floats(float* p, int n) {
    int i = blockIdx.x * 256 + threadIdx.x;
    if (i < n) p[i] = 0.f;
}

// ---------------- runtime format probes ----------------
__global__ void detect_flags(const unsigned* xw, const int* ei, int* flags) {
    __shared__ int cnt, nz;
    if (threadIdx.x == 0) { cnt = 0; nz = 0; }
    __syncthreads();
    unsigned u = xw[threadIdx.x];
    float av = fabsf(bf2f(u & 0xffffu));
    if (av > 1e-5f && av < 50.f) atomicAdd(&cnt, 1);
    if (ei[2 * threadIdx.x + 1] != 0) atomicAdd(&nz, 1);
    __syncthreads();
    if (threadIdx.x == 0) {
        flags[0] = (cnt >= 128) ? 0 : 1;           // 1 = inputs are float32
        if (nz == 0) { flags[1] = 2; flags[2] = 2 * N_EDGES; }
        else         { flags[1] = 1; flags[2] = N_EDGES; }
    }
}

// ---------------- weight transpose: Wt[n][k] = bf16(W[k][n]) ----------------
__global__ void transpose_w(const void* W0, const void* W1, const void* W2, const void* W3,
                            bf16u* Wt, const int* flags) {
    __shared__ bf16u tile[64][65];
    int isf32 = flags[0];
    const void* W = (blockIdx.y == 0) ? W0 : (blockIdx.y == 1) ? W1 : (blockIdx.y == 2) ? W2 : W3;
    bf16u* out = Wt + (size_t)blockIdx.y * DIM * DIM;
    int t = threadIdx.x;
    int tx = t & 63, ty = t >> 6;
    int k0 = (blockIdx.x >> 2) * 64, n0 = (blockIdx.x & 3) * 64;
#pragma unroll
    for (int i = 0; i < 16; ++i) {
        int r = ty + i * 4;
        tile[tx][r] = f2bf(loadv(W, (size_t)(k0 + r) * DIM + (n0 + tx), isf32));
    }
    __syncthreads();
#pragma unroll
    for (int i = 0; i < 16; ++i) {
        int r = ty + i * 4;
        out[(size_t)(n0 + r) * DIM + (k0 + tx)] = tile[r][tx];
    }
}

// ---------------- BN0 column stats (dual dtype input) ----------------
__global__ void col_stats(const void* X, int nrows, float* sums, const int* flags, int dual) {
    __shared__ float ls[512];
    int isf32 = dual ? flags[0] : 0;
    int t = threadIdx.x;
    ls[t] = 0.f; ls[t + 256] = 0.f;
    __syncthreads();
    int rpb = (nrows + gridDim.x - 1) / gridDim.x;
    int r0 = blockIdx.x * rpb;
    int r1 = r0 + rpb; if (r1 > nrows) r1 = nrows;
    int cg = (t & 31) * 8;
    float s[8], q[8];
#pragma unroll
    for (int j = 0; j < 8; ++j) { s[j] = 0.f; q[j] = 0.f; }
    for (int r = r0 + (t >> 5); r < r1; r += 8) {
        size_t base = (size_t)r * DIM + cg;
#pragma unroll
        for (int j = 0; j < 8; ++j) {
            float f = loadv(X, base + j, isf32);
            s[j] += f; q[j] += f * f;
        }
    }
#pragma unroll
    for (int j = 0; j < 8; ++j) {
        atomicAdd(&ls[cg + j], s[j]);
        atomicAdd(&ls[256 + cg + j], q[j]);
    }
    __syncthreads();
    atomicAdd(&sums[t], ls[t]);
    atomicAdd(&sums[256 + t], ls[256 + t]);
}

__global__ void bn_finalize(const float* sums, const void* gamma, const void* beta,
                            float* sc, float* sh, float inv_n, const int* flags) {
    int isf32 = flags[0];
    int t = threadIdx.x;
    float mu = sums[t] * inv_n;
    float var = sums[256 + t] * inv_n - mu * mu;
    float rs = rsqrtf(var + 1e-5f);
    float g = loadv(gamma, t, isf32), b = loadv(beta, t, isf32);
    sc[t] = rs * g;
    sh[t] = b - mu * rs * g;
}

// ---------------- vectorized BN apply: y = relu?(x*sc+sh), writes bf16 ----------------
__global__ void bn_apply(const void* X, const float* sc, const float* sh, bf16u* Y,
                         const int* flags, int dual, int relu) {
    int isf32 = dual ? flags[0] : 0;
    size_t i = (size_t)blockIdx.x * 256 + threadIdx.x;
    int c = ((int)(i & 31)) * 8;
    size_t base = i * 8;
    float v[8];
    if (isf32) {
        f32x4 x0 = *(const f32x4*)((const float*)X + base);
        f32x4 x1 = *(const f32x4*)((const float*)X + base + 4);
#pragma unroll
        for (int j = 0; j < 4; ++j) { v[j] = x0[j]; v[4 + j] = x1[j]; }
    } else {
        uint4 u = *(const uint4*)((const bf16u*)X + base);
        v[0] = bf2f(u.x & 0xffffu); v[1] = bf2f(u.x >> 16);
        v[2] = bf2f(u.y & 0xffffu); v[3] = bf2f(u.y >> 16);
        v[4] = bf2f(u.z & 0xffffu); v[5] = bf2f(u.z >> 16);
        v[6] = bf2f(u.w & 0xffffu); v[7] = bf2f(u.w >> 16);
    }
    f32x4 s0 = *(const f32x4*)(sc + c), s1 = *(const f32x4*)(sc + c + 4);
    f32x4 h0 = *(const f32x4*)(sh + c), h1 = *(const f32x4*)(sh + c + 4);
    float y[8];
#pragma unroll
    for (int j = 0; j < 4; ++j) {
        y[j]     = v[j]     * s0[j] + h0[j];
        y[4 + j] = v[4 + j] * s1[j] + h1[j];
    }
    if (relu) {
#pragma unroll
        for (int j = 0; j < 8; ++j) y[j] = fmaxf(y[j], 0.f);
    }
    uint4 ov;
    ov.x = (unsigned)f2bf(y[0]) | ((unsigned)f2bf(y[1]) << 16);
    ov.y = (unsigned)f2bf(y[2]) | ((unsigned)f2bf(y[3]) << 16);
    ov.z = (unsigned)f2bf(y[4]) | ((unsigned)f2bf(y[5]) << 16);
    ov.w = (unsigned)f2bf(y[6]) | ((unsigned)f2bf(y[7]) << 16);
    *(uint4*)(Y + base) = ov;
}

// ---------------- CSR build ----------------
__global__ void edge_hist(const int* ei, const int* flags, int* deg) {
    int e = blockIdx.x * 256 + threadIdx.x;
    if (e < N_EDGES) atomicAdd(&deg[ei[(size_t)flags[2] + (size_t)e * flags[1]]], 1);
}

__global__ void scan1(const int* deg, int* rp, int* bsum) {
    __shared__ int s[256];
    int t = threadIdx.x;
    int i = blockIdx.x * 256 + t;
    s[t] = (i < N_NODES) ? deg[i] : 0;
    __syncthreads();
    for (int off = 1; off < 256; off <<= 1) {
        int nv = (t >= off) ? s[t - off] : 0;
        __syncthreads();
        s[t] += nv;
        __syncthreads();
    }
    if (i < N_NODES) rp[i + 1] = s[t];
    if (t == 255) bsum[blockIdx.x] = s[255];
}

__global__ void scan2(int* bsum, int nblocks) {
    __shared__ int s[512];
    int t = threadIdx.x;
    s[t] = (t < nblocks) ? bsum[t] : 0;
    __syncthreads();
    for (int off = 1; off < 512; off <<= 1) {
        int nv = (t >= off) ? s[t - off] : 0;
        __syncthreads();
        s[t] += nv;
        __syncthreads();
    }
    if (t < nblocks) bsum[t] = s[t];
}

__global__ void scan3(int* rp, const int* bsum) {
    int i = blockIdx.x * 256 + threadIdx.x;
    if (i == 0) rp[0] = 0;
    if (i < N_NODES) {
        int b = i >> 8;
        if (b > 0) rp[i + 1] += bsum[b - 1];
    }
}

__global__ void csr_fill(const int* ei, const int* flags, const int* rp, int* fill, int* col) {
    int e = blockIdx.x * 256 + threadIdx.x;
    if (e < N_EDGES) {
        int d = ei[(size_t)flags[2] + (size_t)e * flags[1]];
        int s = ei[(size_t)e * flags[1]];
        int p = rp[d] + atomicAdd(&fill[d], 1);
        col[p] = s;
    }
}

// ---------------- aggregation, unroll-4 for MLP ----------------
__global__ void aggregate(const bf16u* h, const int* rp, const int* col, bf16u* out) {
    int node = blockIdx.x * 4 + (threadIdx.x >> 6);
    int lane = threadIdx.x & 63;
    const uint2* hv = (const uint2*)h;            // 8B units, 64 per row
    uint2 u = hv[(size_t)node * 64 + lane];
    float a0 = bf2f(u.x & 0xffffu), a1 = bf2f(u.x >> 16);
    float a2 = bf2f(u.y & 0xffffu), a3 = bf2f(u.y >> 16);
    float b0 = 0.f, b1 = 0.f, b2 = 0.f, b3 = 0.f;
    float c0 = 0.f, c1 = 0.f, c2 = 0.f, c3 = 0.f;
    float d0 = 0.f, d1 = 0.f, d2 = 0.f, d3 = 0.f;
    int e = rp[node], e1 = rp[node + 1];
    for (; e + 4 <= e1; e += 4) {
        int s0 = col[e], s1 = col[e + 1], s2 = col[e + 2], s3 = col[e + 3];
        uint2 w0 = hv[(size_t)s0 * 64 + lane];
        uint2 w1 = hv[(size_t)s1 * 64 + lane];
        uint2 w2 = hv[(size_t)s2 * 64 + lane];
        uint2 w3 = hv[(size_t)s3 * 64 + lane];
        a0 += bf2f(w0.x & 0xffffu); a1 += bf2f(w0.x >> 16); a2 += bf2f(w0.y & 0xffffu); a3 += bf2f(w0.y >> 16);
        b0 += bf2f(w1.x & 0xffffu); b1 += bf2f(w1.x >> 16); b2 += bf2f(w1.y & 0xffffu); b3 += bf2f(w1.y >> 16);
        c0 += bf2f(w2.x & 0xffffu); c1 += bf2f(w2.x >> 16); c2 += bf2f(w2.y & 0xffffu); c3 += bf2f(w2.y >> 16);
        d0 += bf2f(w3.x & 0xffffu); d1 += bf2f(w3.x >> 16); d2 += bf2f(w3.y & 0xffffu); d3 += bf2f(w3.y >> 16);
    }
    for (; e < e1; ++e) {
        uint2 w0 = hv[(size_t)col[e] * 64 + lane];
        a0 += bf2f(w0.x & 0xffffu); a1 += bf2f(w0.x >> 16); a2 += bf2f(w0.y & 0xffffu); a3 += bf2f(w0.y >> 16);
    }
    a0 += b0 + (c0 + d0); a1 += b1 + (c1 + d1);
    a2 += b2 + (c2 + d2); a3 += b3 + (c3 + d3);
    uint2 ov;
    ov.x = (unsigned)f2bf(a0) | ((unsigned)f2bf(a1) << 16);
    ov.y = (unsigned)f2bf(a2) | ((unsigned)f2bf(a3) << 16);
    *(uint2*)&((uint2*)out)[(size_t)node * 64 + lane] = ov;
}

// ---------------- MFMA GEMM, BK=64, async staging, XOR bank swizzle ----------------
// Wt bf16 [n][k]. Optional fused column stats (sum/sumsq of f32 outputs) via atomics.
__global__ __launch_bounds__(256) void gemm_bias(const bf16u* __restrict__ A,
                                                 const bf16u* __restrict__ Wt,
                                                 const void* __restrict__ bias,
                                                 void* __restrict__ Cout, int mrows,
                                                 const int* __restrict__ flags,
                                                 int relu, int f32out,
                                                 float* __restrict__ stats) {
    __shared__ bf16u As[128 * 64];   // 16 KB, row stride 64 elems, k-chunks XOR-swizzled
    __shared__ bf16u Bs[128 * 64];
    __shared__ float lsum[256];      // [0..127] col sums, [128..255] col sumsq
    int isf32 = flags[0];
    int t = threadIdx.x;
    int w = t >> 6, lane = t & 63;
    int lr = lane & 15, lq = lane >> 4;
    int wm = w >> 1, wn = w & 1;
    int rowBase = blockIdx.x * 128, colBase = blockIdx.y * 128;
    f32x4 acc[4][4] = {};
    lsum[t] = 0.f;
    // staging: lane t covers row (t>>3), slot (t&7); global chunk g = slot ^ (row&7)
    int srow = t >> 3;                       // 0..31 (per 32-row pass)
    int g8   = ((t & 7) ^ ((t >> 3) & 7)) * 8;  // swizzled k element offset
    for (int k0 = 0; k0 < 256; k0 += 64) {
        __syncthreads();
#pragma unroll
        for (int p = 0; p < 4; ++p) {
            int r = p * 32 + srow;
            int gr = rowBase + r; gr = (gr < mrows) ? gr : (mrows - 1);
            async_copy16(A + (size_t)gr * 256 + k0 + g8, &As[(p * 32 + (w << 3)) * 64]);
            async_copy16(Wt + (size_t)(colBase + r) * 256 + k0 + g8, &Bs[(p * 32 + (w << 3)) * 64]);
        }
        __syncthreads();
#pragma unroll
        for (int ks = 0; ks < 2; ++ks) {
            bf16x8s af[4], bfv[4];
#pragma unroll
            for (int mt = 0; mt < 4; ++mt) {
                int ar = wm * 64 + mt * 16 + lr;
                af[mt] = *(const bf16x8s*)&As[ar * 64 + (((ks * 4 + lq) ^ (lr & 7)) * 8)];
            }
#pragma unroll
            for (int nt = 0; nt < 4; ++nt) {
                int br = wn * 64 + nt * 16 + lr;
                bfv[nt] = *(const bf16x8s*)&Bs[br * 64 + (((ks * 4 + lq) ^ (lr & 7)) * 8)];
            }
#pragma unroll
            for (int mt = 0; mt < 4; ++mt)
#pragma unroll
                for (int nt = 0; nt < 4; ++nt)
                    acc[mt][nt] = __builtin_amdgcn_mfma_f32_16x16x32_bf16(af[mt], bfv[nt], acc[mt][nt], 0, 0, 0);
        }
    }
    int storef32 = f32out && isf32;
#pragma unroll
    for (int nt = 0; nt < 4; ++nt) {
        int cl = wn * 64 + nt * 16 + lr;
        int c = colBase + cl;
        float bv = loadv(bias, c, isf32);
        float ssum = 0.f, ssq = 0.f;
#pragma unroll
        for (int mt = 0; mt < 4; ++mt) {
            int r0 = rowBase + wm * 64 + mt * 16 + lq * 4;
#pragma unroll
            for (int j = 0; j < 4; ++j) {
                int r = r0 + j;
                if (r < mrows) {
                    float y = acc[mt][nt][j] + bv;
                    if (relu) y = fmaxf(y, 0.f);
                    if (storef32) ((float*)Cout)[(size_t)r * 256 + c] = y;
                    else          ((bf16u*)Cout)[(size_t)r * 256 + c] = f2bf(y);
                    ssum += y; ssq += y * y;
                }
            }
        }
        if (stats) {
            atomicAdd(&lsum[cl], ssum);
            atomicAdd(&lsum[128 + cl], ssq);
        }
    }
    if (stats) {
        __syncthreads();
        if (t < 128) {
            atomicAdd(&stats[colBase + t], lsum[t]);
            atomicAdd(&stats[256 + colBase + t], lsum[128 + t]);
        }
    }
}

extern "C" void kernel_launch(void* const* d_in, const int* in_sizes, int n_in,
                              void* d_out, int out_size, void* d_ws, size_t ws_size,
                              hipStream_t stream) {
    const void* x   = d_in[0];
    const int*  ei  = (const int*)d_in[1];
    const void* g0  = d_in[2];
    const void* b0  = d_in[3];
    const void* W1a = d_in[4];
    const void* b1a = d_in[5];
    const void* g1  = d_in[6];
    const void* bt1 = d_in[7];
    const void* W1b = d_in[8];
    const void* b1b = d_in[9];
    const void* W2a = d_in[10];
    const void* b2a = d_in[11];
    const void* g2  = d_in[12];
    const void* bt2 = d_in[13];
    const void* W2b = d_in[14];
    const void* b2b = d_in[15];

    char* ws = (char*)d_ws;
    size_t off = 0;
    auto alloc = [&](size_t bytes) {
        char* p = ws + off;
        off += (bytes + 255) & ~(size_t)255;
        return p;
    };
    const size_t FB = (size_t)N_NODES * DIM * 2;
    bf16u* bufA  = (bf16u*)alloc(FB);
    bf16u* bufB  = (bf16u*)alloc(FB);
    bf16u* Wt    = (bf16u*)alloc((size_t)4 * DIM * DIM * 2);
    int*   colA  = (int*)alloc((size_t)N_EDGES * 4);
    int*   rp    = (int*)alloc((size_t)(N_NODES + 1) * 4);
    int*   deg   = (int*)alloc((size_t)N_NODES * 4);
    int*   fill  = (int*)alloc((size_t)N_NODES * 4);
    int*   bsum  = (int*)alloc(512 * 4);
    float* sums0 = (float*)alloc(512 * 4);
    float* sums1 = (float*)alloc(512 * 4);
    float* sums2 = (float*)alloc(512 * 4);
    float* sc    = (float*)alloc(256 * 4);
    float* sh    = (float*)alloc(256 * 4);
    int*   flags = (int*)alloc(4 * 4);

    bf16u* Wt1a = Wt;
    bf16u* Wt1b = Wt + 65536;
    bf16u* Wt2a = Wt + 2 * 65536;
    bf16u* Wt2b = Wt + 3 * 65536;

    const float inv_n = 1.0f / (float)N_NODES;

    detect_flags<<<1, 256, 0, stream>>>((const unsigned*)x, ei, flags);
    zero_floats<<<6, 256, 0, stream>>>(sums0, 1536);   // sums0..sums2 contiguous
    transpose_w<<<dim3(16, 4), 256, 0, stream>>>(W1a, W1b, W2a, W2b, Wt, flags);

    zero_ints<<<391, 256, 0, stream>>>(deg, N_NODES);
    zero_ints<<<391, 256, 0, stream>>>(fill, N_NODES);
    edge_hist<<<6250, 256, 0, stream>>>(ei, flags, deg);
    scan1<<<391, 256, 0, stream>>>(deg, rp, bsum);
    scan2<<<1, 512, 0, stream>>>(bsum, 391);
    scan3<<<392, 256, 0, stream>>>(rp, bsum);
    csr_fill<<<6250, 256, 0, stream>>>(ei, flags, rp, fill, colA);

    // BN0: x (f32) -> bufB (bf16)
    col_stats<<<500, 256, 0, stream>>>(x, N_NODES, sums0, flags, 1);
    bn_finalize<<<1, 256, 0, stream>>>(sums0, g0, b0, sc, sh, inv_n, flags);
    bn_apply<<<12500, 256, 0, stream>>>(x, sc, sh, bufB, flags, 1, 0);

    // layer 1
    aggregate<<<25000, 256, 0, stream>>>(bufB, rp, colA, bufA);
    gemm_bias<<<dim3(782, 2), 256, 0, stream>>>(bufA, Wt1a, b1a, bufB, N_NODES, flags, 0, 0, sums1);
    bn_finalize<<<1, 256, 0, stream>>>(sums1, g1, bt1, sc, sh, inv_n, flags);
    bn_apply<<<12500, 256, 0, stream>>>(bufB, sc, sh, bufB, flags, 0, 1);
    gemm_bias<<<dim3(782, 2), 256, 0, stream>>>(bufB, Wt1b, b1b, bufA, N_NODES, flags, 1, 0, nullptr);

    // layer 2
    aggregate<<<25000, 256, 0, stream>>>(bufA, rp, colA, bufB);
    gemm_bias<<<dim3(782, 2), 256, 0, stream>>>(bufB, Wt2a, b2a, bufA, N_NODES, flags, 0, 0, sums2);
    bn_finalize<<<1, 256, 0, stream>>>(sums2, g2, bt2, sc, sh, inv_n, flags);
    bn_apply<<<12500, 256, 0, stream>>>(bufA, sc, sh, bufA, flags, 0, 1);
    gemm_bias<<<dim3(782, 2), 256, 0, stream>>>(bufA, Wt2b, b2b, d_out, N_NODES, flags, 1, 1, nullptr);
}